// Round 1
// baseline (512.297 us; speedup 1.0000x reference)
//
#include <hip/hip_runtime.h>
#include <math.h>

#define T_FIRE 3000
#define B_SZ 16
#define C_CH 32
#define HID 128
#define NF 128
#define H_SW 32
#define W_SW 375
#define DSW 192
#define DM 512
#define P_POLY 32
#define DP 32

#define ALPHA_BLOCKS (B_SZ * T_FIRE / 4)   // 12000

typedef __attribute__((ext_vector_type(8))) short bf16x8;
typedef __attribute__((ext_vector_type(4))) float f32x4;

__device__ inline short f2bf(float f) {
    union { float f; unsigned u; } v; v.f = f;
    unsigned r = v.u + 0x7FFF + ((v.u >> 16) & 1);   // RNE
    return (short)(r >> 16);
}

__device__ inline bf16x8 load_afrag(const float* __restrict__ p) {
    float4 x = *(const float4*)p;
    float4 y = *(const float4*)(p + 4);
    bf16x8 f;
    f[0] = f2bf(x.x); f[1] = f2bf(x.y); f[2] = f2bf(x.z); f[3] = f2bf(x.w);
    f[4] = f2bf(y.x); f[5] = f2bf(y.y); f[6] = f2bf(y.z); f[7] = f2bf(y.w);
    return f;
}

// ---------------- K1: alpha (blocks < 12000) + weight pack (blocks >= 12000)
// alpha = softplus(proj(relu(dense(LN(conv+res)))))
// pack: Bpack[ks][ct][lane][j] = W[ks*32 + (lane>>4)*8 + j][ct*16 + (lane&15)]
__global__ __launch_bounds__(256) void alpha_pack_kernel(
    const float* __restrict__ fs, const float* __restrict__ conv_w,
    const float* __restrict__ ln_w, const float* __restrict__ ln_b,
    const float* __restrict__ dense_w, const float* __restrict__ dense_b,
    const float* __restrict__ proj_w, const float* __restrict__ proj_b,
    float* __restrict__ alpha_out,
    const float* __restrict__ pw, const float* __restrict__ sww,
    short* __restrict__ bp_p, short* __restrict__ bp_s)
{
    if (blockIdx.x >= ALPHA_BLOCKS) {
        // ---- pack path: 56 blocks, 14336 lane-tasks ----
        int t = (blockIdx.x - ALPHA_BLOCKS) * 256 + threadIdx.x;
        if (t < 12288) {
            int lane = t & 63;
            int ct = (t >> 6) & 31;
            int ks = t >> 11;
            int k0 = ks * 32 + (lane >> 4) * 8;
            int n  = ct * 16 + (lane & 15);
            bf16x8 v;
#pragma unroll
            for (int j = 0; j < 8; j++) v[j] = f2bf(sww[(k0 + j) * DM + n]);
            *(bf16x8*)(bp_s + (long)t * 8) = v;
        } else if (t < 14336) {
            int u = t - 12288;
            int lane = u & 63;
            int ct = u >> 6;
            int k0 = (lane >> 4) * 8;
            int n  = ct * 16 + (lane & 15);
            bf16x8 v;
#pragma unroll
            for (int j = 0; j < 8; j++) v[j] = f2bf(pw[(k0 + j) * DM + n]);
            *(bf16x8*)(bp_p + (long)u * 8) = v;
        }
        return;
    }

    // ---- alpha path ----
    int lane = threadIdx.x & 63;
    int wave = threadIdx.x >> 6;
    int r = blockIdx.x * 4 + wave;
    int b = r / T_FIRE, t = r - b * T_FIRE;
    int c = lane & 31;
    long base = ((long)(b * T_FIRE + t)) * C_CH + c;
    float xc = fs[base];
    float xm = (t > 0)          ? fs[base - C_CH] : 0.f;
    float xp = (t < T_FIRE - 1) ? fs[base + C_CH] : 0.f;
    float w0 = conv_w[c * 3 + 0], w1 = conv_w[c * 3 + 1], w2 = conv_w[c * 3 + 2];
    float x = xc + xm * w0 + xc * w1 + xp * w2;
    float s = x, s2 = x * x;
#pragma unroll
    for (int o = 1; o < 64; o <<= 1) { s += __shfl_xor(s, o); s2 += __shfl_xor(s2, o); }
    float mean = s * (1.f / 64.f);
    float var  = s2 * (1.f / 64.f) - mean * mean;
    float xn = (x - mean) * rsqrtf(var + 1e-5f) * ln_w[c] + ln_b[c];
    float a0 = dense_b[lane], a1 = dense_b[lane + 64];
#pragma unroll
    for (int cc = 0; cc < 32; cc++) {
        float xv = __shfl(xn, cc);
        a0 = fmaf(xv, dense_w[cc * HID + lane], a0);
        a1 = fmaf(xv, dense_w[cc * HID + lane + 64], a1);
    }
    a0 = fmaxf(a0, 0.f);
    a1 = fmaxf(a1, 0.f);
    float v = a0 * proj_w[lane] + a1 * proj_w[lane + 64];
#pragma unroll
    for (int o = 1; o < 64; o <<= 1) v += __shfl_xor(v, o);
    if (lane == 0) {
        float z = v + proj_b[0];
        alpha_out[r] = fmaxf(z, 0.f) + log1pf(expf(-fabsf(z)));
    }
}

// ---------------- K2: fires scan + qty partials -----------------------------
__global__ __launch_bounds__(1024) void fires_kernel(
    const float* __restrict__ alpha, const int* __restrict__ target,
    int* __restrict__ fw, float* __restrict__ qpart)
{
    __shared__ int wtot[16];
    __shared__ int sbase;
    __shared__ float ssig[16];
    int b = blockIdx.x, tid = threadIdx.x;
    int lane = tid & 63, w = tid >> 6;
    if (tid < NF) fw[b * NF + tid] = (T_FIRE - 1) >> 3;   // 374 = padded slots
    if (tid == 0) sbase = 0;
    float psig = 0.f;
    __syncthreads();
    for (int chunk = 0; chunk < 3; chunk++) {
        int idx = chunk * 1024 + tid;
        bool valid = idx < T_FIRE;
        float a = valid ? alpha[b * T_FIRE + idx] : 0.f;
        if (valid) psig += 1.f / (1.f + expf(-(a - 1.0f) * 10.f));
        bool flag = valid && (a > 1.0f);
        unsigned long long mask = __ballot(flag);
        int prefix = __popcll(mask & ((1ull << lane) - 1ull));
        if (lane == 0) wtot[w] = __popcll(mask);
        __syncthreads();
        if (tid == 0) {
            int run = sbase;
            for (int i = 0; i < 16; i++) { int v2 = wtot[i]; wtot[i] = run; run += v2; }
            sbase = run;
        }
        __syncthreads();
        int rank = wtot[w] + prefix;
        if (flag && rank < NF) fw[b * NF + rank] = idx >> 3;
        __syncthreads();
    }
#pragma unroll
    for (int o = 1; o < 64; o <<= 1) psig += __shfl_xor(psig, o);
    if (lane == 0) ssig[w] = psig;
    __syncthreads();
    if (tid == 0) {
        float tot = 0.f;
        for (int i = 0; i < 16; i++) tot += ssig[i];
        qpart[b] = fabsf(tot - (float)target[b]);
    }
}

// ---------------- K3: fused acoustic tokens (pitch + swin) via MFMA ---------
// block = one (b,n): 64 rows x 512 cols. 8 waves:
//   sec = w>>2 (0 pitch rows 0-31 | 1 swin rows 32-63), band=(w>>1)&1, ch=w&1.
// Each wave: 16 accum tiles 16x16 (64 VGPR), A-frags from global fp32
// (converted in-reg, swin A prefetched up-front to hide the fw-dependent
// HBM gather once instead of 6x), B-frags from packed bf16 (coalesced
// 16B/lane). Output via nontemporal stores so the 268 MB stream does not
// evict the packed-B working set from L2. Block 0 also finalizes qty_loss.
__global__ __launch_bounds__(512) void tok_kernel(
    const float* __restrict__ pt, const float* __restrict__ sw2d,
    const short* __restrict__ bp_p, const short* __restrict__ bp_s,
    const float* __restrict__ pb, const float* __restrict__ swb,
    const int* __restrict__ fw, float* __restrict__ acoustic,
    const float* __restrict__ qpart, float* __restrict__ qty_out)
{
    int bn = blockIdx.x;                 // 0..2047
    int b  = bn >> 7;
    int w    = threadIdx.x >> 6;         // 0..7
    int lane = threadIdx.x & 63;
    int quad = lane >> 4, m16 = lane & 15;
    int sec  = w >> 2;
    int band = (w >> 1) & 1;
    int ch   = w & 1;

    if (bn == 0 && threadIdx.x == 0) {
        float tot = 0.f;
        for (int i = 0; i < B_SZ; i++) tot += qpart[i];
        qty_out[0] = tot * (1.f / B_SZ);
    }

    f32x4 acc[16];
#pragma unroll
    for (int i = 0; i < 16; i++) acc[i] = (f32x4){0.f, 0.f, 0.f, 0.f};

    if (sec == 0) {
        // pitch: A = pitch_tokens[b,n] 32x32, K=32 -> one k-step
        const float* arow = pt + ((long)bn * 32 + band * 16 + m16) * DP + quad * 8;
        bf16x8 af = load_afrag(arow);
        const bf16x8* bpp = (const bf16x8*)bp_p;
#pragma unroll
        for (int ct = 0; ct < 16; ct++) {
            bf16x8 bf_ = bpp[(long)(ch * 16 + ct) * 64 + lane];
            acc[ct] = __builtin_amdgcn_mfma_f32_16x16x32_bf16(af, bf_, acc[ct], 0, 0, 0);
        }
    } else {
        // swin: A row m = swin_2d[b, band*16+m16, wcol, :], K=192 -> 6 k-steps
        // Prefetch ALL six A-frags (contiguous 768 B/row) before the MFMA
        // loop: one exposed gather latency instead of six serial ones.
        int wcol = fw[bn];
        const float* arow =
            sw2d + (((long)(b * H_SW + band * 16 + m16)) * W_SW + wcol) * DSW + quad * 8;
        bf16x8 af[6];
#pragma unroll
        for (int ks = 0; ks < 6; ks++) af[ks] = load_afrag(arow + ks * 32);
        const bf16x8* bps = (const bf16x8*)bp_s;
#pragma unroll 1
        for (int ks = 0; ks < 6; ks++) {
#pragma unroll
            for (int ct = 0; ct < 16; ct++) {
                bf16x8 bf_ = bps[(long)(ks * 32 + ch * 16 + ct) * 64 + lane];
                acc[ct] = __builtin_amdgcn_mfma_f32_16x16x32_bf16(af[ks], bf_, acc[ct], 0, 0, 0);
            }
        }
    }

    // epilogue: C/D layout col = lane&15, row = quad*4 + r
    const float* bias = (sec == 0) ? pb : swb;
    long rowbase = ((long)bn * 64 + sec * 32 + band * 16 + quad * 4) * DM;
#pragma unroll
    for (int ct = 0; ct < 16; ct++) {
        int col = ch * 256 + ct * 16 + m16;
        float bv = bias[col];
#pragma unroll
        for (int r = 0; r < 4; r++)
            __builtin_nontemporal_store(acc[ct][r] + bv,
                                        &acoustic[rowbase + (long)r * DM + col]);
    }
}

extern "C" void kernel_launch(void* const* d_in, const int* in_sizes, int n_in,
                              void* d_out, int out_size, void* d_ws, size_t ws_size,
                              hipStream_t stream)
{
    const float* fs      = (const float*)d_in[0];
    const float* swin2d  = (const float*)d_in[1];
    const float* pt      = (const float*)d_in[2];
    const int*   target  = (const int*)d_in[3];
    const float* conv_w  = (const float*)d_in[4];
    const float* ln_w    = (const float*)d_in[5];
    const float* ln_b    = (const float*)d_in[6];
    const float* dense_w = (const float*)d_in[7];
    const float* dense_b = (const float*)d_in[8];
    const float* proj_w  = (const float*)d_in[9];
    const float* proj_b  = (const float*)d_in[10];
    const float* pitch_w = (const float*)d_in[11];
    const float* pitch_b = (const float*)d_in[12];
    const float* swin_w  = (const float*)d_in[13];
    const float* swin_b  = (const float*)d_in[14];

    float* out      = (float*)d_out;
    float* acoustic = out;                                   // 16*128*64*512
    float* alpha    = out + (long)B_SZ * NF * 64 * DM;       // 48000
    float* qty      = alpha + B_SZ * T_FIRE;                 // 1

    char* ws = (char*)d_ws;
    int*   fw    = (int*)ws;                                  ws += B_SZ * NF * sizeof(int);
    float* qpart = (float*)ws;                                ws += 64 * sizeof(float);
    short* bp_s  = (short*)ws;                                ws += (long)DSW * DM * sizeof(short);
    short* bp_p  = (short*)ws;                                ws += (long)DP * DM * sizeof(short);

    alpha_pack_kernel<<<ALPHA_BLOCKS + 56, 256, 0, stream>>>(
        fs, conv_w, ln_w, ln_b, dense_w, dense_b, proj_w, proj_b, alpha,
        pitch_w, swin_w, bp_p, bp_s);
    fires_kernel<<<B_SZ, 1024, 0, stream>>>(alpha, target, fw, qpart);
    tok_kernel<<<B_SZ * NF, 512, 0, stream>>>(
        pt, swin2d, bp_p, bp_s, pitch_b, swin_b, fw, acoustic, qpart, qty);
}

// Round 2
// 458.712 us; speedup vs baseline: 1.1168x; 1.1168x over previous
//
#include <hip/hip_runtime.h>
#include <math.h>

#define T_FIRE 3000
#define B_SZ 16
#define C_CH 32
#define HID 128
#define NF 128
#define H_SW 32
#define W_SW 375
#define DSW 192
#define DM 512
#define P_POLY 32
#define DP 32

#define ALPHA_BLOCKS (B_SZ * T_FIRE / 4)   // 12000

typedef __attribute__((ext_vector_type(8))) short bf16x8;
typedef __attribute__((ext_vector_type(4))) float f32x4;

__device__ inline short f2bf(float f) {
    union { float f; unsigned u; } v; v.f = f;
    unsigned r = v.u + 0x7FFF + ((v.u >> 16) & 1);   // RNE
    return (short)(r >> 16);
}

__device__ inline bf16x8 load_afrag(const float* __restrict__ p) {
    float4 x = *(const float4*)p;
    float4 y = *(const float4*)(p + 4);
    bf16x8 f;
    f[0] = f2bf(x.x); f[1] = f2bf(x.y); f[2] = f2bf(x.z); f[3] = f2bf(x.w);
    f[4] = f2bf(y.x); f[5] = f2bf(y.y); f[6] = f2bf(y.z); f[7] = f2bf(y.w);
    return f;
}

// ---------------- K1: alpha (blocks < 12000) + weight pack (blocks >= 12000)
// alpha = softplus(proj(relu(dense(LN(conv+res)))))
// pack: Bpack[ks][ct][lane][j] = W[ks*32 + (lane>>4)*8 + j][ct*16 + (lane&15)]
__global__ __launch_bounds__(256) void alpha_pack_kernel(
    const float* __restrict__ fs, const float* __restrict__ conv_w,
    const float* __restrict__ ln_w, const float* __restrict__ ln_b,
    const float* __restrict__ dense_w, const float* __restrict__ dense_b,
    const float* __restrict__ proj_w, const float* __restrict__ proj_b,
    float* __restrict__ alpha_out,
    const float* __restrict__ pw, const float* __restrict__ sww,
    short* __restrict__ bp_p, short* __restrict__ bp_s)
{
    if (blockIdx.x >= ALPHA_BLOCKS) {
        // ---- pack path: 56 blocks, 14336 lane-tasks ----
        int t = (blockIdx.x - ALPHA_BLOCKS) * 256 + threadIdx.x;
        if (t < 12288) {
            int lane = t & 63;
            int ct = (t >> 6) & 31;
            int ks = t >> 11;
            int k0 = ks * 32 + (lane >> 4) * 8;
            int n  = ct * 16 + (lane & 15);
            bf16x8 v;
#pragma unroll
            for (int j = 0; j < 8; j++) v[j] = f2bf(sww[(k0 + j) * DM + n]);
            *(bf16x8*)(bp_s + (long)t * 8) = v;
        } else if (t < 14336) {
            int u = t - 12288;
            int lane = u & 63;
            int ct = u >> 6;
            int k0 = (lane >> 4) * 8;
            int n  = ct * 16 + (lane & 15);
            bf16x8 v;
#pragma unroll
            for (int j = 0; j < 8; j++) v[j] = f2bf(pw[(k0 + j) * DM + n]);
            *(bf16x8*)(bp_p + (long)u * 8) = v;
        }
        return;
    }

    // ---- alpha path ----
    int lane = threadIdx.x & 63;
    int wave = threadIdx.x >> 6;
    int r = blockIdx.x * 4 + wave;
    int b = r / T_FIRE, t = r - b * T_FIRE;
    int c = lane & 31;
    long base = ((long)(b * T_FIRE + t)) * C_CH + c;
    float xc = fs[base];
    float xm = (t > 0)          ? fs[base - C_CH] : 0.f;
    float xp = (t < T_FIRE - 1) ? fs[base + C_CH] : 0.f;
    float w0 = conv_w[c * 3 + 0], w1 = conv_w[c * 3 + 1], w2 = conv_w[c * 3 + 2];
    float x = xc + xm * w0 + xc * w1 + xp * w2;
    float s = x, s2 = x * x;
#pragma unroll
    for (int o = 1; o < 64; o <<= 1) { s += __shfl_xor(s, o); s2 += __shfl_xor(s2, o); }
    float mean = s * (1.f / 64.f);
    float var  = s2 * (1.f / 64.f) - mean * mean;
    float xn = (x - mean) * rsqrtf(var + 1e-5f) * ln_w[c] + ln_b[c];
    float a0 = dense_b[lane], a1 = dense_b[lane + 64];
#pragma unroll
    for (int cc = 0; cc < 32; cc++) {
        float xv = __shfl(xn, cc);
        a0 = fmaf(xv, dense_w[cc * HID + lane], a0);
        a1 = fmaf(xv, dense_w[cc * HID + lane + 64], a1);
    }
    a0 = fmaxf(a0, 0.f);
    a1 = fmaxf(a1, 0.f);
    float v = a0 * proj_w[lane] + a1 * proj_w[lane + 64];
#pragma unroll
    for (int o = 1; o < 64; o <<= 1) v += __shfl_xor(v, o);
    if (lane == 0) {
        float z = v + proj_b[0];
        alpha_out[r] = fmaxf(z, 0.f) + log1pf(expf(-fabsf(z)));
    }
}

// ---------------- K2: fires scan + qty partials -----------------------------
__global__ __launch_bounds__(1024) void fires_kernel(
    const float* __restrict__ alpha, const int* __restrict__ target,
    int* __restrict__ fw, float* __restrict__ qpart)
{
    __shared__ int wtot[16];
    __shared__ int sbase;
    __shared__ float ssig[16];
    int b = blockIdx.x, tid = threadIdx.x;
    int lane = tid & 63, w = tid >> 6;
    if (tid < NF) fw[b * NF + tid] = (T_FIRE - 1) >> 3;   // 374 = padded slots
    if (tid == 0) sbase = 0;
    float psig = 0.f;
    __syncthreads();
    for (int chunk = 0; chunk < 3; chunk++) {
        int idx = chunk * 1024 + tid;
        bool valid = idx < T_FIRE;
        float a = valid ? alpha[b * T_FIRE + idx] : 0.f;
        if (valid) psig += 1.f / (1.f + expf(-(a - 1.0f) * 10.f));
        bool flag = valid && (a > 1.0f);
        unsigned long long mask = __ballot(flag);
        int prefix = __popcll(mask & ((1ull << lane) - 1ull));
        if (lane == 0) wtot[w] = __popcll(mask);
        __syncthreads();
        if (tid == 0) {
            int run = sbase;
            for (int i = 0; i < 16; i++) { int v2 = wtot[i]; wtot[i] = run; run += v2; }
            sbase = run;
        }
        __syncthreads();
        int rank = wtot[w] + prefix;
        if (flag && rank < NF) fw[b * NF + rank] = idx >> 3;
        __syncthreads();
    }
#pragma unroll
    for (int o = 1; o < 64; o <<= 1) psig += __shfl_xor(psig, o);
    if (lane == 0) ssig[w] = psig;
    __syncthreads();
    if (tid == 0) {
        float tot = 0.f;
        for (int i = 0; i < 16; i++) tot += ssig[i];
        qpart[b] = fabsf(tot - (float)target[b]);
    }
}

// ---------------- K3: fused acoustic tokens (pitch + swin) via MFMA ---------
// block = one (b,n): 64 rows x 512 cols. 8 waves:
//   sec = w>>2 (0 pitch rows 0-31 | 1 swin rows 32-63), band=(w>>1)&1, ch=w&1.
// Each wave: 16 accum tiles 16x16 (64 VGPR), A-frags from global fp32
// (converted in-reg), B-frags from packed bf16 (coalesced 16B/lane). No LDS.
// __launch_bounds__(512,4): cap VGPR at 128 -> 4 waves/SIMD (2 blocks/CU) to
// hide B-frag L2 latency + store drain. acc=64 VGPR leaves 64 for the rest.
// Block 0 also finalizes qty_loss (stream order guarantees qpart ready).
__global__ __launch_bounds__(512, 4) void tok_kernel(
    const float* __restrict__ pt, const float* __restrict__ sw2d,
    const short* __restrict__ bp_p, const short* __restrict__ bp_s,
    const float* __restrict__ pb, const float* __restrict__ swb,
    const int* __restrict__ fw, float* __restrict__ acoustic,
    const float* __restrict__ qpart, float* __restrict__ qty_out)
{
    int bn = blockIdx.x;                 // 0..2047
    int b  = bn >> 7;
    int w    = threadIdx.x >> 6;         // 0..7
    int lane = threadIdx.x & 63;
    int quad = lane >> 4, m16 = lane & 15;
    int sec  = w >> 2;
    int band = (w >> 1) & 1;
    int ch   = w & 1;

    if (bn == 0 && threadIdx.x == 0) {
        float tot = 0.f;
        for (int i = 0; i < B_SZ; i++) tot += qpart[i];
        qty_out[0] = tot * (1.f / B_SZ);
    }

    f32x4 acc[16];
#pragma unroll
    for (int i = 0; i < 16; i++) acc[i] = (f32x4){0.f, 0.f, 0.f, 0.f};

    if (sec == 0) {
        // pitch: A = pitch_tokens[b,n] 32x32, K=32 -> one k-step
        const float* arow = pt + ((long)bn * 32 + band * 16 + m16) * DP + quad * 8;
        bf16x8 af = load_afrag(arow);
        const bf16x8* bpp = (const bf16x8*)bp_p;
#pragma unroll
        for (int ct = 0; ct < 16; ct++) {
            bf16x8 bf_ = bpp[(long)(ch * 16 + ct) * 64 + lane];
            acc[ct] = __builtin_amdgcn_mfma_f32_16x16x32_bf16(af, bf_, acc[ct], 0, 0, 0);
        }
    } else {
        // swin: A row m = swin_2d[b, band*16+m16, wcol, :], K=192 -> 6 k-steps
        int wcol = fw[bn];
        const float* arow =
            sw2d + (((long)(b * H_SW + band * 16 + m16)) * W_SW + wcol) * DSW + quad * 8;
        const bf16x8* bps = (const bf16x8*)bp_s;
#pragma unroll 1
        for (int ks = 0; ks < 6; ks++) {
            bf16x8 af = load_afrag(arow + ks * 32);
#pragma unroll
            for (int ct = 0; ct < 16; ct++) {
                bf16x8 bf_ = bps[(long)(ks * 32 + ch * 16 + ct) * 64 + lane];
                acc[ct] = __builtin_amdgcn_mfma_f32_16x16x32_bf16(af, bf_, acc[ct], 0, 0, 0);
            }
        }
    }

    // epilogue: C/D layout col = lane&15, row = quad*4 + r
    const float* bias = (sec == 0) ? pb : swb;
    long rowbase = ((long)bn * 64 + sec * 32 + band * 16 + quad * 4) * DM;
#pragma unroll
    for (int ct = 0; ct < 16; ct++) {
        int col = ch * 256 + ct * 16 + m16;
        float bv = bias[col];
#pragma unroll
        for (int r = 0; r < 4; r++)
            acoustic[rowbase + (long)r * DM + col] = acc[ct][r] + bv;
    }
}

extern "C" void kernel_launch(void* const* d_in, const int* in_sizes, int n_in,
                              void* d_out, int out_size, void* d_ws, size_t ws_size,
                              hipStream_t stream)
{
    const float* fs      = (const float*)d_in[0];
    const float* swin2d  = (const float*)d_in[1];
    const float* pt      = (const float*)d_in[2];
    const int*   target  = (const int*)d_in[3];
    const float* conv_w  = (const float*)d_in[4];
    const float* ln_w    = (const float*)d_in[5];
    const float* ln_b    = (const float*)d_in[6];
    const float* dense_w = (const float*)d_in[7];
    const float* dense_b = (const float*)d_in[8];
    const float* proj_w  = (const float*)d_in[9];
    const float* proj_b  = (const float*)d_in[10];
    const float* pitch_w = (const float*)d_in[11];
    const float* pitch_b = (const float*)d_in[12];
    const float* swin_w  = (const float*)d_in[13];
    const float* swin_b  = (const float*)d_in[14];

    float* out      = (float*)d_out;
    float* acoustic = out;                                   // 16*128*64*512
    float* alpha    = out + (long)B_SZ * NF * 64 * DM;       // 48000
    float* qty      = alpha + B_SZ * T_FIRE;                 // 1

    char* ws = (char*)d_ws;
    int*   fw    = (int*)ws;                                  ws += B_SZ * NF * sizeof(int);
    float* qpart = (float*)ws;                                ws += 64 * sizeof(float);
    short* bp_s  = (short*)ws;                                ws += (long)DSW * DM * sizeof(short);
    short* bp_p  = (short*)ws;                                ws += (long)DP * DM * sizeof(short);

    alpha_pack_kernel<<<ALPHA_BLOCKS + 56, 256, 0, stream>>>(
        fs, conv_w, ln_w, ln_b, dense_w, dense_b, proj_w, proj_b, alpha,
        pitch_w, swin_w, bp_p, bp_s);
    fires_kernel<<<B_SZ, 1024, 0, stream>>>(alpha, target, fw, qpart);
    tok_kernel<<<B_SZ * NF, 512, 0, stream>>>(
        pt, swin2d, bp_p, bp_s, pitch_b, swin_b, fw, acoustic, qpart, qty);
}